// Round 11
// baseline (4783.040 us; speedup 1.0000x reference)
//
#include <hip/hip_runtime.h>
#include <math.h>

#define N 4096
#define D 512
#define L 128

// ---------------- fast path (needs ~144 MB ws) ----------------
#define DTI 128
#define DTJ 128
#define DKD 8              // d per chunk; dbuf total = 17408 B -> 6+ blocks/CU
#define NCH (D / DKD)      // 64 chunks
#define DAS 132            // A LDS stride (f32)
#define DBS 140            // B LDS stride; 140%32=12 -> staging writes 2-way
                           // (free, m136) vs 144's 4-way
#define BUF_FLOATS (DKD * (DAS + DBS))  // 2176 floats = 8704 B per buffer

// ---------------- fallback path (R3, ~25 MB ws) ----------------
#define PARTS 16
#define PARTJ (N / PARTS)
#define TI 128
#define TJ 64
#define KD 32
#define AS_STRIDE (TI + 4)
#define BS_STRIDE (TJ + 4)
#define DS_STRIDE (TJ + 4)
#define SMEM_FLOATS (TI * DS_STRIDE)

// acc += |t| in exactly one VOP3 instr (abs input modifier). R9/R10 showed
// the f16 dot2 path has a hidden pipe penalty — fp32 VOP3 is the fast core.
#define ACC_ABS(accv, t) \
  asm("v_add_f32 %0, %0, abs(%1)" : "+v"(accv) : "v"(t))

// Insert v into ascending sorted tk[0..15], dropping the old max.
__device__ __forceinline__ void topk_insert(float (&tk)[16], float v) {
  float x = v;
#pragma unroll
  for (int k = 0; k < 16; ++k) {
    float lo = fminf(x, tk[k]);
    float hi = fmaxf(x, tk[k]);
    tk[k] = lo;
    x = hi;
  }
}

// rec = latent @ W + b ; grid (N/8, 2), block 256.
__global__ __launch_bounds__(256) void linear_kernel(
    const float* __restrict__ lat_test, const float* __restrict__ lat_train,
    const float* __restrict__ W, const float* __restrict__ bias,
    float* __restrict__ rec_test, float* __restrict__ rec_train) {
  const float* __restrict__ lat = blockIdx.y ? lat_train : lat_test;
  float* __restrict__ out = blockIdx.y ? rec_train : rec_test;
  const int r0 = blockIdx.x * 8;
  const int t = threadIdx.x;

  __shared__ float ls[8 * L];
  {
    float4 v = *(const float4*)(lat + (size_t)r0 * L + t * 4);
    *(float4*)&ls[t * 4] = v;
  }
  __syncthreads();

  float acc[8][2];
#pragma unroll
  for (int r = 0; r < 8; ++r) { acc[r][0] = 0.f; acc[r][1] = 0.f; }

#pragma unroll 4
  for (int l = 0; l < L; ++l) {
    float w0 = W[l * D + t];
    float w1 = W[l * D + t + 256];
#pragma unroll
    for (int r = 0; r < 8; ++r) {
      float x = ls[r * L + l];
      acc[r][0] = fmaf(x, w0, acc[r][0]);
      acc[r][1] = fmaf(x, w1, acc[r][1]);
    }
  }
  float b0 = bias[t], b1 = bias[t + 256];
#pragma unroll
  for (int r = 0; r < 8; ++r) {
    out[(size_t)(r0 + r) * D + t] = acc[r][0] + b0;
    out[(size_t)(r0 + r) * D + t + 256] = acc[r][1] + b1;
  }
}

// ============ FAST PATH ============
// L1 cdist, 128x128 tile, 8x8/thread, fp32 abs-add core (R7-proven),
// LDS double-buffer with reg prefetch, DKD=8 so LDS=17408 B, and
// waves_per_eu(6,6) -> 6 blocks/CU (24 waves) to hide dependency bubbles.
// (6,6) VGPR cap ~80 >= natural ~64: no R2-style squeeze.
__global__ __launch_bounds__(256) __attribute__((amdgpu_waves_per_eu(6, 6)))
void dist_kernel(const float* __restrict__ Arec, const float* __restrict__ Bgt,
                 const float* __restrict__ Btr, float* __restrict__ dist) {
  const int i0 = blockIdx.x * DTI;
  const int j0 = blockIdx.y * DTJ;
  const int mat = blockIdx.z;
  const float* __restrict__ B = mat ? Btr : Bgt;
  float* __restrict__ out = dist + (size_t)mat * N * N;

  __shared__ float smem[2][BUF_FLOATS];  // 17408 B total

  const int tid = threadIdx.x;
  const int tx = tid & 15;
  const int ty = tid >> 4;
  const int aoff = 8 * ty;
  const int boff = 8 * tx + 4 * (tx >> 2);  // swizzled column base

  // staging map: chunk = 128 rows x 8 d per array = 256 float4; 1/thread each
  const int r0 = tid >> 1;        // 0..127
  const int c4 = tid & 1;         // float4 group within 8-d chunk
  const int jw0 = r0 + 4 * (r0 >> 5);  // swizzled B column
  const float* apA0 = Arec + (size_t)(i0 + r0) * D + c4 * 4;
  const float* bp0 = B + (size_t)(j0 + r0) * D + c4 * 4;

  float acc[8][8];
#pragma unroll
  for (int r = 0; r < 8; ++r)
#pragma unroll
    for (int c = 0; c < 8; ++c) acc[r][c] = 0.f;

#define STAGE(buf)                                                     \
  {                                                                    \
    float* As = smem[buf];                                             \
    float* Bs = As + DKD * DAS;                                        \
    As[(4 * c4 + 0) * DAS + r0] = va0.x;                               \
    As[(4 * c4 + 1) * DAS + r0] = va0.y;                               \
    As[(4 * c4 + 2) * DAS + r0] = va0.z;                               \
    As[(4 * c4 + 3) * DAS + r0] = va0.w;                               \
    Bs[(4 * c4 + 0) * DBS + jw0] = vb0.x;                              \
    Bs[(4 * c4 + 1) * DBS + jw0] = vb0.y;                              \
    Bs[(4 * c4 + 2) * DBS + jw0] = vb0.z;                              \
    Bs[(4 * c4 + 3) * DBS + jw0] = vb0.w;                              \
  }

  // prologue: chunk 0 -> buffer 0
  float4 va0 = *(const float4*)(apA0);
  float4 vb0 = *(const float4*)(bp0);
  STAGE(0)

#pragma unroll 1
  for (int chunk = 0; chunk < NCH; ++chunk) {
    __syncthreads();  // buf[chunk&1] staged for everyone
    if (chunk + 1 < NCH) {  // prefetch next chunk into regs
      const int off = (chunk + 1) * DKD;
      va0 = *(const float4*)(apA0 + off);
      vb0 = *(const float4*)(bp0 + off);
    }

    const float* As = smem[chunk & 1];
    const float* Bs = As + DKD * DAS;
#pragma unroll
    for (int d = 0; d < DKD; ++d) {
      float4 a0 = *(const float4*)&As[d * DAS + aoff];
      float4 a1 = *(const float4*)&As[d * DAS + aoff + 4];
      float4 b0 = *(const float4*)&Bs[d * DBS + boff];
      float4 b1 = *(const float4*)&Bs[d * DBS + boff + 4];
#define ROWC(r, av)                                       \
  {                                                       \
    float t0 = av - b0.x; ACC_ABS(acc[r][0], t0);         \
    float t1 = av - b0.y; ACC_ABS(acc[r][1], t1);         \
    float t2 = av - b0.z; ACC_ABS(acc[r][2], t2);         \
    float t3 = av - b0.w; ACC_ABS(acc[r][3], t3);         \
    float t4 = av - b1.x; ACC_ABS(acc[r][4], t4);         \
    float t5 = av - b1.y; ACC_ABS(acc[r][5], t5);         \
    float t6 = av - b1.z; ACC_ABS(acc[r][6], t6);         \
    float t7 = av - b1.w; ACC_ABS(acc[r][7], t7);         \
  }
      ROWC(0, a0.x) ROWC(1, a0.y) ROWC(2, a0.z) ROWC(3, a0.w)
      ROWC(4, a1.x) ROWC(5, a1.y) ROWC(6, a1.z) ROWC(7, a1.w)
#undef ROWC
    }

    if (chunk + 1 < NCH) STAGE((chunk + 1) & 1)
  }
#undef STAGE

#pragma unroll
  for (int r = 0; r < 8; ++r) {
    float* dst = out + (size_t)(i0 + 8 * ty + r) * N + j0 + 8 * tx;
    *(float4*)dst = make_float4(acc[r][0], acc[r][1], acc[r][2], acc[r][3]);
    *(float4*)(dst + 4) = make_float4(acc[r][4], acc[r][5], acc[r][6], acc[r][7]);
  }
}

// One WAVE per row (4 rows per 256-block): insert-filtered scan of 64/lane,
// then 6 shfl_xor bitonic merge levels. No LDS, no barriers.
__global__ __launch_bounds__(256) void row_topk_kernel(
    const float* __restrict__ dist, float* __restrict__ scores) {
  const int wave = threadIdx.x >> 6;
  const int lane = threadIdx.x & 63;
  const int row = blockIdx.x * 4 + wave;
  const float* __restrict__ p = dist + (size_t)row * N;

  float tk[16];
#pragma unroll
  for (int k = 0; k < 16; ++k) tk[k] = 3.0e38f;

#pragma unroll 1
  for (int q = 0; q < 16; ++q) {
    float4 v = *(const float4*)(p + q * 256 + lane * 4);
    if (v.x < tk[15]) topk_insert(tk, v.x);
    if (v.y < tk[15]) topk_insert(tk, v.y);
    if (v.z < tk[15]) topk_insert(tk, v.z);
    if (v.w < tk[15]) topk_insert(tk, v.w);
  }

#pragma unroll
  for (int m = 1; m < 64; m <<= 1) {
    float oth[16];
#pragma unroll
    for (int k = 0; k < 16; ++k) oth[k] = __shfl_xor(tk[k], m, 64);
    float lo[16];
#pragma unroll
    for (int k = 0; k < 16; ++k) lo[k] = fminf(tk[k], oth[15 - k]);
#pragma unroll
    for (int dlt = 8; dlt >= 1; dlt >>= 1) {
#pragma unroll
      for (int i = 0; i < 16; ++i) {
        if ((i & dlt) == 0 && (i + dlt) < 16) {
          float a = lo[i], b = lo[i + dlt];
          lo[i] = fminf(a, b);
          lo[i + dlt] = fmaxf(a, b);
        }
      }
    }
#pragma unroll
    for (int k = 0; k < 16; ++k) tk[k] = lo[k];
  }

  if (lane == 0) {
    float s = 0.f;
#pragma unroll
    for (int k = 0; k < 16; ++k) s += 1.0f / tk[k];
    scores[row] = s * (1.0f / 16.0f);
  }
}

// ============ FALLBACK PATH (R3, proven, fp32) ============
__global__ __launch_bounds__(256) void dist_topk_kernel(
    const float* __restrict__ Arec, const float* __restrict__ Bgt,
    const float* __restrict__ Btr, float* __restrict__ cand) {
  const int itile = blockIdx.x;
  const int part = blockIdx.y;
  const int mat = blockIdx.z;
  const float* __restrict__ B = mat ? Btr : Bgt;
  const int i0 = itile * TI;
  const int jbase = part * PARTJ;

  __shared__ float smem[SMEM_FLOATS];
  float* As = smem;
  float* Bs = smem + KD * AS_STRIDE;
  float* distS = smem;

  const int tid = threadIdx.x;
  const int tx = tid & 15;
  const int ty = tid >> 4;
  const int srow = tid >> 1;
  const int shalf = tid & 1;
  const int scol = shalf * 32;

  float tk[16];
#pragma unroll
  for (int k = 0; k < 16; ++k) tk[k] = 3.0e38f;

  for (int jc = 0; jc < PARTJ; jc += TJ) {
    float acc[8][4];
#pragma unroll
    for (int r = 0; r < 8; ++r)
#pragma unroll
      for (int c = 0; c < 4; ++c) acc[r][c] = 0.f;

    for (int d0 = 0; d0 < D; d0 += KD) {
      __syncthreads();
#pragma unroll
      for (int s = 0; s < 4; ++s) {
        int f4 = tid + s * 256;
        int r = f4 >> 3;
        int c4i = f4 & 7;
        float4 v = *(const float4*)(Arec + (size_t)(i0 + r) * D + d0 + c4i * 4);
        As[(4 * c4i + 0) * AS_STRIDE + r] = v.x;
        As[(4 * c4i + 1) * AS_STRIDE + r] = v.y;
        As[(4 * c4i + 2) * AS_STRIDE + r] = v.z;
        As[(4 * c4i + 3) * AS_STRIDE + r] = v.w;
      }
#pragma unroll
      for (int s = 0; s < 2; ++s) {
        int f4 = tid + s * 256;
        int r = f4 >> 3;
        int c4i = f4 & 7;
        float4 v = *(const float4*)(B + (size_t)(jbase + jc + r) * D + d0 + c4i * 4);
        Bs[(4 * c4i + 0) * BS_STRIDE + r] = v.x;
        Bs[(4 * c4i + 1) * BS_STRIDE + r] = v.y;
        Bs[(4 * c4i + 2) * BS_STRIDE + r] = v.z;
        Bs[(4 * c4i + 3) * BS_STRIDE + r] = v.w;
      }
      __syncthreads();

#pragma unroll
      for (int d = 0; d < KD; ++d) {
        float4 a0 = *(const float4*)&As[d * AS_STRIDE + 8 * ty];
        float4 a1 = *(const float4*)&As[d * AS_STRIDE + 8 * ty + 4];
        float4 bv4 = *(const float4*)&Bs[d * BS_STRIDE + 4 * tx];
        float av[8] = {a0.x, a0.y, a0.z, a0.w, a1.x, a1.y, a1.z, a1.w};
        float bv[4] = {bv4.x, bv4.y, bv4.z, bv4.w};
#pragma unroll
        for (int r = 0; r < 8; ++r)
#pragma unroll
          for (int c = 0; c < 4; ++c) {
            float t = av[r] - bv[c];
            ACC_ABS(acc[r][c], t);
          }
      }
    }

    __syncthreads();
#pragma unroll
    for (int r = 0; r < 8; ++r)
      *(float4*)&distS[(8 * ty + r) * DS_STRIDE + 4 * tx] =
          make_float4(acc[r][0], acc[r][1], acc[r][2], acc[r][3]);
    __syncthreads();

#pragma unroll 1
    for (int j4 = 0; j4 < 8; ++j4) {
      float4 v = *(const float4*)&distS[srow * DS_STRIDE + scol + j4 * 4];
      if (v.x < tk[15]) topk_insert(tk, v.x);
      if (v.y < tk[15]) topk_insert(tk, v.y);
      if (v.z < tk[15]) topk_insert(tk, v.z);
      if (v.w < tk[15]) topk_insert(tk, v.w);
    }
  }

  __syncthreads();
  float* mergeS = smem;
#pragma unroll
  for (int k4 = 0; k4 < 4; ++k4)
    *(float4*)&mergeS[srow * 32 + shalf * 16 + k4 * 4] =
        make_float4(tk[k4 * 4], tk[k4 * 4 + 1], tk[k4 * 4 + 2], tk[k4 * 4 + 3]);
  __syncthreads();

  if (tid < TI) {
    const float* LA = &mergeS[tid * 32];
    const float* LB = LA + 16;
    const int row = i0 + tid;
    float* dst = cand + ((size_t)((mat * PARTS + part) * N) + row) * 16;
    int ia = 0, ib = 0;
#pragma unroll 1
    for (int k = 0; k < 16; ++k) {
      float a = LA[ia < 16 ? ia : 15];
      float b = LB[ib < 16 ? ib : 15];
      bool takeA = (ib >= 16) || (ia < 16 && a <= b);
      dst[k] = takeA ? a : b;
      ia += takeA ? 1 : 0;
      ib += takeA ? 0 : 1;
    }
  }
}

__global__ __launch_bounds__(256) void merge_kernel(
    const float* __restrict__ cand, float* __restrict__ scores) {
  const int gid = blockIdx.x * 256 + threadIdx.x;
  if (gid >= 2 * N) return;
  const int m = gid >> 12;
  const int row = gid & (N - 1);

  float tk[16];
#pragma unroll
  for (int k = 0; k < 16; ++k) tk[k] = 3.0e38f;

  for (int p = 0; p < PARTS; ++p) {
    const float* lp = cand + ((size_t)((m * PARTS + p) * N) + row) * 16;
#pragma unroll 1
    for (int k = 0; k < 16; ++k) {
      float v = lp[k];
      if (v >= tk[15]) break;
      topk_insert(tk, v);
    }
  }
  float s = 0.f;
#pragma unroll
  for (int k = 0; k < 16; ++k) s += 1.0f / tk[k];
  scores[(size_t)m * N + row] = s * (1.0f / 16.0f);
}

// losses = relu(neg - pos); huber(delta=1) vs 0; mean. Single block.
__global__ __launch_bounds__(256) void loss_kernel(
    const float* __restrict__ scores, float* __restrict__ out) {
  const int tid = threadIdx.x;
  float s = 0.f;
  for (int i = tid; i < N; i += 256) {
    float l = scores[N + i] - scores[i];
    l = fmaxf(l, 0.f);
    s += (l <= 1.f) ? 0.5f * l * l : (l - 0.5f);
  }
#pragma unroll
  for (int off = 32; off > 0; off >>= 1) s += __shfl_down(s, off, 64);
  __shared__ float ws[4];
  if ((tid & 63) == 0) ws[tid >> 6] = s;
  __syncthreads();
  if (tid == 0) {
    float t = ws[0] + ws[1] + ws[2] + ws[3];
    out[0] = t * (1.0f / (float)N);
  }
}

extern "C" void kernel_launch(void* const* d_in, const int* in_sizes, int n_in,
                              void* d_out, int out_size, void* d_ws, size_t ws_size,
                              hipStream_t stream) {
  const float* gt_vals = (const float*)d_in[0];
  const float* train_latent = (const float*)d_in[1];
  const float* test_latent = (const float*)d_in[2];
  const float* W = (const float*)d_in[3];
  const float* b = (const float*)d_in[4];
  float* out = (float*)d_out;

  char* ws = (char*)d_ws;
  const size_t REC = 8388608;          // 8 MB each
  const size_t DIST = 134217728;       // 128 MB
  const size_t NEED_FAST = 2 * REC + DIST + 32768;

  float* rec_test = (float*)(ws);
  float* rec_train = (float*)(ws + REC);

  linear_kernel<<<dim3(N / 8, 2), 256, 0, stream>>>(
      test_latent, train_latent, W, b, rec_test, rec_train);

  if (ws_size >= NEED_FAST) {
    float* dist = (float*)(ws + 2 * REC);
    float* scores = (float*)(ws + 2 * REC + DIST);
    dist_kernel<<<dim3(N / DTI, N / DTJ, 2), 256, 0, stream>>>(
        rec_test, gt_vals, rec_train, dist);
    row_topk_kernel<<<(2 * N) / 4, 256, 0, stream>>>(dist, scores);
    loss_kernel<<<1, 256, 0, stream>>>(scores, out);
  } else {
    float* cand = (float*)(ws + 2 * REC);                 // 8 MB
    float* scores = (float*)(ws + 2 * REC + 8388608);     // 32 KB
    dist_topk_kernel<<<dim3(N / TI, PARTS, 2), 256, 0, stream>>>(
        rec_test, gt_vals, rec_train, cand);
    merge_kernel<<<(2 * N) / 256, 256, 0, stream>>>(cand, scores);
    loss_kernel<<<1, 256, 0, stream>>>(scores, out);
  }
}

// Round 12
// 744.860 us; speedup vs baseline: 6.4214x; 6.4214x over previous
//
#include <hip/hip_runtime.h>
#include <math.h>

#define N 4096
#define D 512
#define L 128

// ---------------- fast path (needs ~144 MB ws) ----------------
#define DTI 128
#define DTJ 128
#define DKD 16            // dbuf chunk (R7-proven structure)
#define NCH (D / DKD)     // 32 chunks
#define DAS 132           // A LDS stride
#define DBS 140           // B LDS stride; 140 (mod32=12) measured 1.68e7
                          // conflict cyc (R9/R10) vs 144's 5.03e7 (R7)
#define BUF_FLOATS (DKD * DAS + DKD * DBS)   // 4352 floats = 17408 B/buffer

// ---------------- fallback path (R3, ~25 MB ws) ----------------
#define PARTS 16
#define PARTJ (N / PARTS)
#define TI 128
#define TJ 64
#define KD 32
#define AS_STRIDE (TI + 4)
#define BS_STRIDE (TJ + 4)
#define DS_STRIDE (TJ + 4)
#define SMEM_FLOATS (TI * DS_STRIDE)

// acc += |t| in exactly one VOP3 instr (abs input modifier).
// Session lessons: f16 dot2 core = hidden pipe penalty (R9/R10);
// occupancy attrs >4 waves/EU = VGPR squeeze + spill (R2/R11).
#define ACC_ABS(accv, t) \
  asm("v_add_f32 %0, %0, abs(%1)" : "+v"(accv) : "v"(t))

// Insert v into ascending sorted tk[0..15], dropping the old max.
__device__ __forceinline__ void topk_insert(float (&tk)[16], float v) {
  float x = v;
#pragma unroll
  for (int k = 0; k < 16; ++k) {
    float lo = fminf(x, tk[k]);
    float hi = fmaxf(x, tk[k]);
    tk[k] = lo;
    x = hi;
  }
}

// rec = latent @ W + b ; grid (N/8, 2), block 256.
__global__ __launch_bounds__(256) void linear_kernel(
    const float* __restrict__ lat_test, const float* __restrict__ lat_train,
    const float* __restrict__ W, const float* __restrict__ bias,
    float* __restrict__ rec_test, float* __restrict__ rec_train) {
  const float* __restrict__ lat = blockIdx.y ? lat_train : lat_test;
  float* __restrict__ out = blockIdx.y ? rec_train : rec_test;
  const int r0 = blockIdx.x * 8;
  const int t = threadIdx.x;

  __shared__ float ls[8 * L];
  {
    float4 v = *(const float4*)(lat + (size_t)r0 * L + t * 4);
    *(float4*)&ls[t * 4] = v;
  }
  __syncthreads();

  float acc[8][2];
#pragma unroll
  for (int r = 0; r < 8; ++r) { acc[r][0] = 0.f; acc[r][1] = 0.f; }

#pragma unroll 4
  for (int l = 0; l < L; ++l) {
    float w0 = W[l * D + t];
    float w1 = W[l * D + t + 256];
#pragma unroll
    for (int r = 0; r < 8; ++r) {
      float x = ls[r * L + l];
      acc[r][0] = fmaf(x, w0, acc[r][0]);
      acc[r][1] = fmaf(x, w1, acc[r][1]);
    }
  }
  float b0 = bias[t], b1 = bias[t + 256];
#pragma unroll
  for (int r = 0; r < 8; ++r) {
    out[(size_t)(r0 + r) * D + t] = acc[r][0] + b0;
    out[(size_t)(r0 + r) * D + t + 256] = acc[r][1] + b1;
  }
}

// ============ FAST PATH ============
// L1 cdist, 128x128 tile, 8x8/thread, fp32 abs-add core, LDS double-buffer
// with reg prefetch (R7 structure, best measured: 661 us). Only delta vs R7:
// DBS 144 -> 140 (conflict fix, measured in R9/R10).
__global__ __launch_bounds__(256) __attribute__((amdgpu_waves_per_eu(4, 4)))
void dist_kernel(const float* __restrict__ Arec, const float* __restrict__ Bgt,
                 const float* __restrict__ Btr, float* __restrict__ dist) {
  const int i0 = blockIdx.x * DTI;
  const int j0 = blockIdx.y * DTJ;
  const int mat = blockIdx.z;
  const float* __restrict__ B = mat ? Btr : Bgt;
  float* __restrict__ out = dist + (size_t)mat * N * N;

  __shared__ float smem[2][BUF_FLOATS];  // 34816 B -> 4 blocks/CU

  const int tid = threadIdx.x;
  const int tx = tid & 15;
  const int ty = tid >> 4;
  const int aoff = 8 * ty;
  const int boff = 8 * tx + 4 * (tx >> 2);  // swizzled column base

  // staging map: chunk = 128 rows x 16 d = 512 float4 per array, 2/thread each
  const int r0 = tid >> 2;        // 0..63
  const int r1 = r0 + 64;         // 64..127
  const int c4 = tid & 3;         // float4 index within 16-d chunk
  const int jw0 = r0 + 4 * (r0 >> 5);  // swizzled B columns
  const int jw1 = r1 + 4 * (r1 >> 5);
  const float* apA0 = Arec + (size_t)(i0 + r0) * D + c4 * 4;
  const float* apA1 = Arec + (size_t)(i0 + r1) * D + c4 * 4;
  const float* bp0 = B + (size_t)(j0 + r0) * D + c4 * 4;
  const float* bp1 = B + (size_t)(j0 + r1) * D + c4 * 4;

  float acc[8][8];
#pragma unroll
  for (int r = 0; r < 8; ++r)
#pragma unroll
    for (int c = 0; c < 8; ++c) acc[r][c] = 0.f;

#define STAGE(buf)                                                     \
  {                                                                    \
    float* As = smem[buf];                                             \
    float* Bs = As + DKD * DAS;                                        \
    As[(4 * c4 + 0) * DAS + r0] = va0.x;                               \
    As[(4 * c4 + 1) * DAS + r0] = va0.y;                               \
    As[(4 * c4 + 2) * DAS + r0] = va0.z;                               \
    As[(4 * c4 + 3) * DAS + r0] = va0.w;                               \
    As[(4 * c4 + 0) * DAS + r1] = va1.x;                               \
    As[(4 * c4 + 1) * DAS + r1] = va1.y;                               \
    As[(4 * c4 + 2) * DAS + r1] = va1.z;                               \
    As[(4 * c4 + 3) * DAS + r1] = va1.w;                               \
    Bs[(4 * c4 + 0) * DBS + jw0] = vb0.x;                              \
    Bs[(4 * c4 + 1) * DBS + jw0] = vb0.y;                              \
    Bs[(4 * c4 + 2) * DBS + jw0] = vb0.z;                              \
    Bs[(4 * c4 + 3) * DBS + jw0] = vb0.w;                              \
    Bs[(4 * c4 + 0) * DBS + jw1] = vb1.x;                              \
    Bs[(4 * c4 + 1) * DBS + jw1] = vb1.y;                              \
    Bs[(4 * c4 + 2) * DBS + jw1] = vb1.z;                              \
    Bs[(4 * c4 + 3) * DBS + jw1] = vb1.w;                              \
  }

  // prologue: chunk 0 -> buffer 0
  float4 va0 = *(const float4*)(apA0);
  float4 va1 = *(const float4*)(apA1);
  float4 vb0 = *(const float4*)(bp0);
  float4 vb1 = *(const float4*)(bp1);
  STAGE(0)

#pragma unroll 1
  for (int chunk = 0; chunk < NCH; ++chunk) {
    __syncthreads();  // buf[chunk&1] fully staged for everyone
    if (chunk + 1 < NCH) {  // prefetch next chunk into regs
      const int off = (chunk + 1) * DKD;
      va0 = *(const float4*)(apA0 + off);
      va1 = *(const float4*)(apA1 + off);
      vb0 = *(const float4*)(bp0 + off);
      vb1 = *(const float4*)(bp1 + off);
    }

    const float* As = smem[chunk & 1];
    const float* Bs = As + DKD * DAS;
#pragma unroll 4
    for (int d = 0; d < DKD; ++d) {
      float4 a0 = *(const float4*)&As[d * DAS + aoff];
      float4 a1 = *(const float4*)&As[d * DAS + aoff + 4];
      float4 b0 = *(const float4*)&Bs[d * DBS + boff];
      float4 b1 = *(const float4*)&Bs[d * DBS + boff + 4];
#define ROWC(r, av)                                       \
  {                                                       \
    float t0 = av - b0.x; ACC_ABS(acc[r][0], t0);         \
    float t1 = av - b0.y; ACC_ABS(acc[r][1], t1);         \
    float t2 = av - b0.z; ACC_ABS(acc[r][2], t2);         \
    float t3 = av - b0.w; ACC_ABS(acc[r][3], t3);         \
    float t4 = av - b1.x; ACC_ABS(acc[r][4], t4);         \
    float t5 = av - b1.y; ACC_ABS(acc[r][5], t5);         \
    float t6 = av - b1.z; ACC_ABS(acc[r][6], t6);         \
    float t7 = av - b1.w; ACC_ABS(acc[r][7], t7);         \
  }
      ROWC(0, a0.x) ROWC(1, a0.y) ROWC(2, a0.z) ROWC(3, a0.w)
      ROWC(4, a1.x) ROWC(5, a1.y) ROWC(6, a1.z) ROWC(7, a1.w)
#undef ROWC
    }

    if (chunk + 1 < NCH) STAGE((chunk + 1) & 1)
  }
#undef STAGE

#pragma unroll
  for (int r = 0; r < 8; ++r) {
    float* dst = out + (size_t)(i0 + 8 * ty + r) * N + j0 + 8 * tx;
    *(float4*)dst = make_float4(acc[r][0], acc[r][1], acc[r][2], acc[r][3]);
    *(float4*)(dst + 4) = make_float4(acc[r][4], acc[r][5], acc[r][6], acc[r][7]);
  }
}

// One WAVE per row (4 rows per 256-block): insert-filtered scan of 64/lane,
// then 6 shfl_xor bitonic merge levels. No LDS, no barriers.
__global__ __launch_bounds__(256) void row_topk_kernel(
    const float* __restrict__ dist, float* __restrict__ scores) {
  const int wave = threadIdx.x >> 6;
  const int lane = threadIdx.x & 63;
  const int row = blockIdx.x * 4 + wave;
  const float* __restrict__ p = dist + (size_t)row * N;

  float tk[16];
#pragma unroll
  for (int k = 0; k < 16; ++k) tk[k] = 3.0e38f;

#pragma unroll 1
  for (int q = 0; q < 16; ++q) {
    float4 v = *(const float4*)(p + q * 256 + lane * 4);
    if (v.x < tk[15]) topk_insert(tk, v.x);
    if (v.y < tk[15]) topk_insert(tk, v.y);
    if (v.z < tk[15]) topk_insert(tk, v.z);
    if (v.w < tk[15]) topk_insert(tk, v.w);
  }

#pragma unroll
  for (int m = 1; m < 64; m <<= 1) {
    float oth[16];
#pragma unroll
    for (int k = 0; k < 16; ++k) oth[k] = __shfl_xor(tk[k], m, 64);
    float lo[16];
#pragma unroll
    for (int k = 0; k < 16; ++k) lo[k] = fminf(tk[k], oth[15 - k]);
#pragma unroll
    for (int dlt = 8; dlt >= 1; dlt >>= 1) {
#pragma unroll
      for (int i = 0; i < 16; ++i) {
        if ((i & dlt) == 0 && (i + dlt) < 16) {
          float a = lo[i], b = lo[i + dlt];
          lo[i] = fminf(a, b);
          lo[i + dlt] = fmaxf(a, b);
        }
      }
    }
#pragma unroll
    for (int k = 0; k < 16; ++k) tk[k] = lo[k];
  }

  if (lane == 0) {
    float s = 0.f;
#pragma unroll
    for (int k = 0; k < 16; ++k) s += 1.0f / tk[k];
    scores[row] = s * (1.0f / 16.0f);
  }
}

// ============ FALLBACK PATH (R3, proven, fp32) ============
__global__ __launch_bounds__(256) void dist_topk_kernel(
    const float* __restrict__ Arec, const float* __restrict__ Bgt,
    const float* __restrict__ Btr, float* __restrict__ cand) {
  const int itile = blockIdx.x;
  const int part = blockIdx.y;
  const int mat = blockIdx.z;
  const float* __restrict__ B = mat ? Btr : Bgt;
  const int i0 = itile * TI;
  const int jbase = part * PARTJ;

  __shared__ float smem[SMEM_FLOATS];
  float* As = smem;
  float* Bs = smem + KD * AS_STRIDE;
  float* distS = smem;

  const int tid = threadIdx.x;
  const int tx = tid & 15;
  const int ty = tid >> 4;
  const int srow = tid >> 1;
  const int shalf = tid & 1;
  const int scol = shalf * 32;

  float tk[16];
#pragma unroll
  for (int k = 0; k < 16; ++k) tk[k] = 3.0e38f;

  for (int jc = 0; jc < PARTJ; jc += TJ) {
    float acc[8][4];
#pragma unroll
    for (int r = 0; r < 8; ++r)
#pragma unroll
      for (int c = 0; c < 4; ++c) acc[r][c] = 0.f;

    for (int d0 = 0; d0 < D; d0 += KD) {
      __syncthreads();
#pragma unroll
      for (int s = 0; s < 4; ++s) {
        int f4 = tid + s * 256;
        int r = f4 >> 3;
        int c4i = f4 & 7;
        float4 v = *(const float4*)(Arec + (size_t)(i0 + r) * D + d0 + c4i * 4);
        As[(4 * c4i + 0) * AS_STRIDE + r] = v.x;
        As[(4 * c4i + 1) * AS_STRIDE + r] = v.y;
        As[(4 * c4i + 2) * AS_STRIDE + r] = v.z;
        As[(4 * c4i + 3) * AS_STRIDE + r] = v.w;
      }
#pragma unroll
      for (int s = 0; s < 2; ++s) {
        int f4 = tid + s * 256;
        int r = f4 >> 3;
        int c4i = f4 & 7;
        float4 v = *(const float4*)(B + (size_t)(jbase + jc + r) * D + d0 + c4i * 4);
        Bs[(4 * c4i + 0) * BS_STRIDE + r] = v.x;
        Bs[(4 * c4i + 1) * BS_STRIDE + r] = v.y;
        Bs[(4 * c4i + 2) * BS_STRIDE + r] = v.z;
        Bs[(4 * c4i + 3) * BS_STRIDE + r] = v.w;
      }
      __syncthreads();

#pragma unroll
      for (int d = 0; d < KD; ++d) {
        float4 a0 = *(const float4*)&As[d * AS_STRIDE + 8 * ty];
        float4 a1 = *(const float4*)&As[d * AS_STRIDE + 8 * ty + 4];
        float4 bv4 = *(const float4*)&Bs[d * BS_STRIDE + 4 * tx];
        float av[8] = {a0.x, a0.y, a0.z, a0.w, a1.x, a1.y, a1.z, a1.w};
        float bv[4] = {bv4.x, bv4.y, bv4.z, bv4.w};
#pragma unroll
        for (int r = 0; r < 8; ++r)
#pragma unroll
          for (int c = 0; c < 4; ++c) {
            float t = av[r] - bv[c];
            ACC_ABS(acc[r][c], t);
          }
      }
    }

    __syncthreads();
#pragma unroll
    for (int r = 0; r < 8; ++r)
      *(float4*)&distS[(8 * ty + r) * DS_STRIDE + 4 * tx] =
          make_float4(acc[r][0], acc[r][1], acc[r][2], acc[r][3]);
    __syncthreads();

#pragma unroll 1
    for (int j4 = 0; j4 < 8; ++j4) {
      float4 v = *(const float4*)&distS[srow * DS_STRIDE + scol + j4 * 4];
      if (v.x < tk[15]) topk_insert(tk, v.x);
      if (v.y < tk[15]) topk_insert(tk, v.y);
      if (v.z < tk[15]) topk_insert(tk, v.z);
      if (v.w < tk[15]) topk_insert(tk, v.w);
    }
  }

  __syncthreads();
  float* mergeS = smem;
#pragma unroll
  for (int k4 = 0; k4 < 4; ++k4)
    *(float4*)&mergeS[srow * 32 + shalf * 16 + k4 * 4] =
        make_float4(tk[k4 * 4], tk[k4 * 4 + 1], tk[k4 * 4 + 2], tk[k4 * 4 + 3]);
  __syncthreads();

  if (tid < TI) {
    const float* LA = &mergeS[tid * 32];
    const float* LB = LA + 16;
    const int row = i0 + tid;
    float* dst = cand + ((size_t)((mat * PARTS + part) * N) + row) * 16;
    int ia = 0, ib = 0;
#pragma unroll 1
    for (int k = 0; k < 16; ++k) {
      float a = LA[ia < 16 ? ia : 15];
      float b = LB[ib < 16 ? ib : 15];
      bool takeA = (ib >= 16) || (ia < 16 && a <= b);
      dst[k] = takeA ? a : b;
      ia += takeA ? 1 : 0;
      ib += takeA ? 0 : 1;
    }
  }
}

__global__ __launch_bounds__(256) void merge_kernel(
    const float* __restrict__ cand, float* __restrict__ scores) {
  const int gid = blockIdx.x * 256 + threadIdx.x;
  if (gid >= 2 * N) return;
  const int m = gid >> 12;
  const int row = gid & (N - 1);

  float tk[16];
#pragma unroll
  for (int k = 0; k < 16; ++k) tk[k] = 3.0e38f;

  for (int p = 0; p < PARTS; ++p) {
    const float* lp = cand + ((size_t)((m * PARTS + p) * N) + row) * 16;
#pragma unroll 1
    for (int k = 0; k < 16; ++k) {
      float v = lp[k];
      if (v >= tk[15]) break;
      topk_insert(tk, v);
    }
  }
  float s = 0.f;
#pragma unroll
  for (int k = 0; k < 16; ++k) s += 1.0f / tk[k];
  scores[(size_t)m * N + row] = s * (1.0f / 16.0f);
}

// losses = relu(neg - pos); huber(delta=1) vs 0; mean. Single block.
__global__ __launch_bounds__(256) void loss_kernel(
    const float* __restrict__ scores, float* __restrict__ out) {
  const int tid = threadIdx.x;
  float s = 0.f;
  for (int i = tid; i < N; i += 256) {
    float l = scores[N + i] - scores[i];
    l = fmaxf(l, 0.f);
    s += (l <= 1.f) ? 0.5f * l * l : (l - 0.5f);
  }
#pragma unroll
  for (int off = 32; off > 0; off >>= 1) s += __shfl_down(s, off, 64);
  __shared__ float ws[4];
  if ((tid & 63) == 0) ws[tid >> 6] = s;
  __syncthreads();
  if (tid == 0) {
    float t = ws[0] + ws[1] + ws[2] + ws[3];
    out[0] = t * (1.0f / (float)N);
  }
}

extern "C" void kernel_launch(void* const* d_in, const int* in_sizes, int n_in,
                              void* d_out, int out_size, void* d_ws, size_t ws_size,
                              hipStream_t stream) {
  const float* gt_vals = (const float*)d_in[0];
  const float* train_latent = (const float*)d_in[1];
  const float* test_latent = (const float*)d_in[2];
  const float* W = (const float*)d_in[3];
  const float* b = (const float*)d_in[4];
  float* out = (float*)d_out;

  char* ws = (char*)d_ws;
  const size_t REC = 8388608;          // 8 MB each
  const size_t DIST = 134217728;       // 128 MB
  const size_t NEED_FAST = 2 * REC + DIST + 32768;

  float* rec_test = (float*)(ws);
  float* rec_train = (float*)(ws + REC);

  linear_kernel<<<dim3(N / 8, 2), 256, 0, stream>>>(
      test_latent, train_latent, W, b, rec_test, rec_train);

  if (ws_size >= NEED_FAST) {
    float* dist = (float*)(ws + 2 * REC);
    float* scores = (float*)(ws + 2 * REC + DIST);
    dist_kernel<<<dim3(N / DTI, N / DTJ, 2), 256, 0, stream>>>(
        rec_test, gt_vals, rec_train, dist);
    row_topk_kernel<<<(2 * N) / 4, 256, 0, stream>>>(dist, scores);
    loss_kernel<<<1, 256, 0, stream>>>(scores, out);
  } else {
    float* cand = (float*)(ws + 2 * REC);                 // 8 MB
    float* scores = (float*)(ws + 2 * REC + 8388608);     // 32 KB
    dist_topk_kernel<<<dim3(N / TI, PARTS, 2), 256, 0, stream>>>(
        rec_test, gt_vals, rec_train, cand);
    merge_kernel<<<(2 * N) / 256, 256, 0, stream>>>(cand, scores);
    loss_kernel<<<1, 256, 0, stream>>>(scores, out);
  }
}